// Round 3
// baseline (2116.513 us; speedup 1.0000x reference)
//
#include <hip/hip_runtime.h>
#include <hip/hip_bf16.h>

// Problem constants (from reference)
#define BATCH 4
#define C_IN 128
#define HW 56
#define L_PIX (HW * HW)      // 3136
#define G_GRP 4
#define CG 32                // channels per group
#define KK 3
#define D_DIM (CG * KK * KK) // 288
#define NG 8
#define OG 32
#define C_OUT 128
#define GRID_MIN -1.0f
#define GRID_H (2.0f / 7.0f) // (max-min)/(NG-1)
#define INV_H 3.5f

__global__ __launch_bounds__(256) void groupkan_kernel(
    const float* __restrict__ x,
    const float* __restrict__ spline_w,
    const float* __restrict__ base_w,
    const float* __restrict__ base_b,
    float* __restrict__ out)
{
    const int tid = threadIdx.x;
    const int l = blockIdx.x * 256 + tid;
    const int bg = blockIdx.y;
    const int b = bg >> 2;
    const int g = bg & 3;
    if (l >= L_PIX) return;

    const int yy = l / HW;
    const int xx = l - yy * HW;

    float acc[OG];
#pragma unroll
    for (int o = 0; o < OG; ++o) acc[o] = base_b[g * OG + o];

    const float* xg  = x + ((size_t)(b * C_IN + g * CG)) * L_PIX;
    const float* swg = spline_w + (size_t)(g * OG) * (D_DIM * NG);
    const float* bwg = base_w + (size_t)(g * OG) * D_DIM;

    for (int c = 0; c < CG; ++c) {
        // gather 3x3 patch for this channel (zero-padded)
        float pv[9];
        const float* xc = xg + c * L_PIX;
#pragma unroll
        for (int kh = 0; kh < 3; ++kh) {
            const int ys = yy + kh - 1;
            const bool yok = (ys >= 0) && (ys < HW);
#pragma unroll
            for (int kw = 0; kw < 3; ++kw) {
                const int xs = xx + kw - 1;
                const bool ok = yok && (xs >= 0) && (xs < HW);
                pv[kh * 3 + kw] = ok ? xc[ys * HW + xs] : 0.0f;
            }
        }

#pragma unroll
        for (int kk = 0; kk < 9; ++kk) {
            const int d = c * 9 + kk;
            const float v = pv[kk];

            // 8 RBF basis values: exp(-((v - c_j)/h)^2)
            float e[NG];
#pragma unroll
            for (int j = 0; j < NG; ++j) {
                const float u = (v - (GRID_MIN + j * GRID_H)) * INV_H;
                e[j] = __expf(-u * u);
            }
            // silu(v)
            const float s = v / (1.0f + __expf(-v));

            const float* sw = swg + d * NG;
            const float* bw = bwg + d;
#pragma unroll
            for (int o = 0; o < OG; ++o) {
                float a = acc[o];
                const float4* w4 =
                    reinterpret_cast<const float4*>(sw + (size_t)o * (D_DIM * NG));
                const float4 w0 = w4[0];
                const float4 w1 = w4[1];
                a += s * bw[(size_t)o * D_DIM];
                a += e[0] * w0.x + e[1] * w0.y + e[2] * w0.z + e[3] * w0.w;
                a += e[4] * w1.x + e[5] * w1.y + e[6] * w1.z + e[7] * w1.w;
                acc[o] = a;
            }
        }
    }

    float* outp = out + ((size_t)(b * C_OUT + g * OG)) * L_PIX + l;
#pragma unroll
    for (int o = 0; o < OG; ++o) outp[(size_t)o * L_PIX] = acc[o];
}

extern "C" void kernel_launch(void* const* d_in, const int* in_sizes, int n_in,
                              void* d_out, int out_size, void* d_ws, size_t ws_size,
                              hipStream_t stream) {
    const float* x        = (const float*)d_in[0];
    const float* spline_w = (const float*)d_in[1];
    const float* base_w   = (const float*)d_in[2];
    const float* base_b   = (const float*)d_in[3];
    float* out = (float*)d_out;

    dim3 grid((L_PIX + 255) / 256, BATCH * G_GRP);
    groupkan_kernel<<<grid, 256, 0, stream>>>(x, spline_w, base_w, base_b, out);
}

// Round 6
// 114.451 us; speedup vs baseline: 18.4927x; 18.4927x over previous
//
#include <hip/hip_runtime.h>

// Problem constants
#define BATCH 4
#define C_IN 128
#define HWD 56
#define L_PIX 3136
#define G_GRP 4
#define CG 32
#define D_DIM 288
#define NG 8
#define OG 32
#define NQ_SPL 72    // spline K-chunks: K = D*NG = 2304 = 72*32
#define NQ_BASE 9    // base   K-chunks: K = D = 288 = 9*32
#define LOG2E 1.44269504f

typedef short  short8 __attribute__((ext_vector_type(8)));
typedef float  f32x4  __attribute__((ext_vector_type(4)));

__device__ __forceinline__ short f2bf(float f) {
    __bf16 h = (__bf16)f;               // RTNE; compiler pairs into v_cvt_pk_bf16_f32
    return __builtin_bit_cast(short, h);
}

// ---------------------------------------------------------------------------
// Prologue: gather+convert weights into per-lane B-fragment order (bf16).
// wspl layout: [G][72][2 otile][64 lane][8]   value = spline_w[g][o][(4q+dl)*8 + j]
// wbase layout:[G][ 9][2 otile][64 lane][8]   value = base_w  [g][o][q*32 + dl*8 + j]
//   with o = otile*16 + (lane&15), dl = lane>>4
// ---------------------------------------------------------------------------
__global__ __launch_bounds__(256) void convert_w_kernel(
    const float* __restrict__ spline_w,
    const float* __restrict__ base_w,
    short* __restrict__ wspl,
    short* __restrict__ wbase)
{
    int t = blockIdx.x * 256 + threadIdx.x;
    if (t >= G_GRP * (NQ_SPL + NQ_BASE) * 2 * 64) return;
    int lane = t & 63;
    int rest = t >> 6;
    int ot = rest & 1;
    int gq = rest >> 1;               // g*81 + q_all
    int g  = gq / (NQ_SPL + NQ_BASE);
    int q  = gq - g * (NQ_SPL + NQ_BASE);
    int o  = ot * 16 + (lane & 15);
    int dl = lane >> 4;
    if (q < NQ_SPL) {
        int d = 4 * q + dl;
        const float* src = spline_w + (size_t)(g * OG + o) * (D_DIM * NG) + d * NG;
        short* dst = wspl + ((size_t)((g * NQ_SPL + q) * 2 + ot) * 64 + lane) * 8;
#pragma unroll
        for (int j = 0; j < 8; ++j) dst[j] = f2bf(src[j]);
    } else {
        int qb = q - NQ_SPL;
        int d0 = qb * 32 + dl * 8;
        const float* src = base_w + (size_t)(g * OG + o) * D_DIM + d0;
        short* dst = wbase + ((size_t)((g * NQ_BASE + qb) * 2 + ot) * 64 + lane) * 8;
#pragma unroll
        for (int j = 0; j < 8; ++j) dst[j] = f2bf(src[j]);
    }
}

// ---------------------------------------------------------------------------
// Main: block = 256 thr = 4 waves; each block: one (b,g) x 64 pixels.
// Wave: 16 pixels x 32 out-channels, K-loop 81 chunks, zero barriers in loop.
// ---------------------------------------------------------------------------
__global__ __launch_bounds__(256, 3) void groupkan_mfma_kernel(
    const float* __restrict__ x,
    const float* __restrict__ base_b,
    const short* __restrict__ wspl,
    const short* __restrict__ wbase,
    float* __restrict__ out)
{
    __shared__ float xt[CG][4][58];   // padded x tile: rows y0-1..y0+2, cols -1..56 (29.7 KB)

    const int tid  = threadIdx.x;
    const int tile = blockIdx.x;      // 0..48   (49*64 = 3136)
    const int bg   = blockIdx.y;      // b*4+g
    const int b = bg >> 2, g = bg & 3;
    const int l0 = tile * 64;
    const int y0 = l0 / HWD;

    // ---- stage x tile (zero-padded halo); pixel rows span <=2 rows (64 = 8t mod 56 <= 48) ----
    const float* xg = x + (size_t)(b * C_IN + g * CG) * L_PIX;
    for (int e = tid; e < CG * 4 * 58; e += 256) {
        int c  = e / 232;
        int r  = e - c * 232;
        int ry = r / 58;
        int rx = r - ry * 58;
        int y  = y0 - 1 + ry;
        int xc = rx - 1;
        float v = 0.0f;
        if (y >= 0 && y < HWD && xc >= 0 && xc < HWD)
            v = xg[(size_t)c * L_PIX + y * HWD + xc];
        xt[c][ry][rx] = v;
    }
    __syncthreads();

    const int lane = tid & 63;
    const int wid  = tid >> 6;
    const int fr   = lane & 15;       // A-row (pixel) AND D-col (channel)
    const int dl   = lane >> 4;       // k-subblock selector
    const int l    = l0 + wid * 16 + fr;
    const int yy   = l / HWD;
    const int xx   = l - yy * HWD;
    const int ybase = yy - y0;        // 0..1

    f32x4 acc0, acc1;
    {
        float b0 = base_b[g * OG + fr];
        float b1 = base_b[g * OG + 16 + fr];
        acc0 = (f32x4){b0, b0, b0, b0};
        acc1 = (f32x4){b1, b1, b1, b1};
    }

    const short8* wspg = (const short8*)wspl + (size_t)g * NQ_SPL * 2 * 64;
    const short8* wbg  = (const short8*)wbase + (size_t)g * NQ_BASE * 2 * 64;

    // ---- spline part: K = 2304, chunk q covers d in [4q, 4q+4), ng 0..7 ----
    // this lane's d = 4q + dl; maintain (c, kk) incrementally: d = c*9 + kk
    int c = 0, kk = dl;
    for (int q = 0; q < NQ_SPL; ++q) {
        int kh = (kk * 11) >> 5;      // kk/3 for kk<9
        int kw = kk - kh * 3;
        float v = xt[c][ybase + kh][xx + kw];
        float v35p = v * 3.5f + 3.5f; // u_j = (v - c_j)*3.5 = v*3.5 + 3.5 - j
        short8 a;
#pragma unroll
        for (int j = 0; j < 8; ++j) {
            float u = v35p - (float)j;
            float e = __builtin_amdgcn_exp2f(u * u * (-LOG2E));   // exp(-u^2)
            a[j] = f2bf(e);
        }
        short8 bf0 = wspg[(q * 2 + 0) * 64 + lane];
        short8 bf1 = wspg[(q * 2 + 1) * 64 + lane];
        acc0 = __builtin_amdgcn_mfma_f32_16x16x32_bf16(a, bf0, acc0, 0, 0, 0);
        acc1 = __builtin_amdgcn_mfma_f32_16x16x32_bf16(a, bf1, acc1, 0, 0, 0);
        kk += 4; if (kk >= 9) { kk -= 9; ++c; }
    }

    // ---- base part: K = 288 (k = d); lane's 8 elems: d = q*32 + dl*8 + j ----
    for (int q = 0; q < NQ_BASE; ++q) {
        int d0 = q * 32 + dl * 8;
        int cc = (d0 * 456) >> 12;    // d0/9 for d0<288
        int kb = d0 - cc * 9;
        short8 a;
#pragma unroll
        for (int j = 0; j < 8; ++j) {
            int kh = (kb * 11) >> 5;
            int kw = kb - kh * 3;
            float v = xt[cc][ybase + kh][xx + kw];
            float ex = __builtin_amdgcn_exp2f(v * (-LOG2E));       // exp(-v)
            float s  = v * __builtin_amdgcn_rcpf(1.0f + ex);       // silu
            a[j] = f2bf(s);
            ++kb; if (kb == 9) { kb = 0; ++cc; }
        }
        short8 bf0 = wbg[(q * 2 + 0) * 64 + lane];
        short8 bf1 = wbg[(q * 2 + 1) * 64 + lane];
        acc0 = __builtin_amdgcn_mfma_f32_16x16x32_bf16(a, bf0, acc0, 0, 0, 0);
        acc1 = __builtin_amdgcn_mfma_f32_16x16x32_bf16(a, bf1, acc1, 0, 0, 0);
    }

    // ---- store: D row=(dl*4+r) -> pixel, col=fr -> channel ----
    float* outp = out + (size_t)(b * C_IN + g * OG) * L_PIX;
    int pix = l0 + wid * 16 + dl * 4;
    *(f32x4*)(outp + (size_t)fr * L_PIX + pix)        = acc0;
    *(f32x4*)(outp + (size_t)(16 + fr) * L_PIX + pix) = acc1;
}

extern "C" void kernel_launch(void* const* d_in, const int* in_sizes, int n_in,
                              void* d_out, int out_size, void* d_ws, size_t ws_size,
                              hipStream_t stream) {
    const float* x        = (const float*)d_in[0];
    const float* spline_w = (const float*)d_in[1];
    const float* base_w   = (const float*)d_in[2];
    const float* base_b   = (const float*)d_in[3];
    float* out = (float*)d_out;

    short* wspl  = (short*)d_ws;                               // 294912 shorts
    short* wbase = wspl + (size_t)G_GRP * NQ_SPL * 2 * 64 * 8; //  36864 shorts

    int conv_threads = G_GRP * (NQ_SPL + NQ_BASE) * 2 * 64;    // 41472
    convert_w_kernel<<<(conv_threads + 255) / 256, 256, 0, stream>>>(
        spline_w, base_w, wspl, wbase);

    dim3 grid(L_PIX / 64, BATCH * G_GRP);                      // 49 x 16
    groupkan_mfma_kernel<<<grid, 256, 0, stream>>>(x, base_b, wspl, wbase, out);
}

// Round 7
// 110.719 us; speedup vs baseline: 19.1161x; 1.0337x over previous
//
#include <hip/hip_runtime.h>

// Problem constants
#define BATCH 4
#define C_IN 128
#define HWD 56
#define L_PIX 3136
#define G_GRP 4
#define CG 32
#define D_DIM 288
#define NG 8
#define OG 32
#define NQ_SPL 72    // spline K-chunks: K = D*NG = 2304 = 72*32
#define NQ_BASE 9    // base   K-chunks: K = D = 288 = 9*32
#define LOG2E 1.44269504f
#define SQRT_L 1.2011224087f      // sqrt(log2 e)
#define A_SCL  4.2039284306f      // 3.5 * SQRT_L

typedef short  short8 __attribute__((ext_vector_type(8)));
typedef float  f32x4  __attribute__((ext_vector_type(4)));
typedef unsigned int u32x4 __attribute__((ext_vector_type(4)));

__device__ __forceinline__ unsigned int pack2(float lo, float hi) {
    unsigned short a = __builtin_bit_cast(unsigned short, (__bf16)lo);
    unsigned short b = __builtin_bit_cast(unsigned short, (__bf16)hi);
    return (unsigned int)a | ((unsigned int)b << 16);
}

// ---------------------------------------------------------------------------
// Prologue: coalesced read of weights, convert to bf16, scatter to per-lane
// B-fragment order. K-permutation (must match main kernel's A generation):
//   spline: chunk q, lane dl, elem j  <->  d = 72*dl + q,      ng = j
//   base:   chunk q, lane dl, elem j  <->  d = 72*dl + 8*q + j
// wspl: [G][72][2 ot][64 lane][8]   wbase: [G][9][2 ot][64 lane][8]
//   o = ot*16 + (lane&15), dl = lane>>4
// ---------------------------------------------------------------------------
#define N_SPL_CHUNK (G_GRP * OG * D_DIM)         // 36864 (8-float chunks)
#define N_BASE_CHUNK (G_GRP * OG * D_DIM / 8)    // 4608

__global__ __launch_bounds__(256) void convert_w_kernel(
    const float* __restrict__ spline_w,
    const float* __restrict__ base_w,
    short* __restrict__ wspl,
    short* __restrict__ wbase)
{
    int t = blockIdx.x * 256 + threadIdx.x;
    if (t >= N_SPL_CHUNK + N_BASE_CHUNK) return;
    if (t < N_SPL_CHUNK) {
        const f32x4* s4 = (const f32x4*)spline_w + (size_t)t * 2;  // coalesced
        f32x4 lo = s4[0], hi = s4[1];
        int flat = t * 8;
        int g = flat / (OG * D_DIM * NG);       // /73728
        int r = flat - g * (OG * D_DIM * NG);
        int o = r / (D_DIM * NG);               // /2304
        int d = (r - o * (D_DIM * NG)) >> 3;
        int dl = d / 72;
        int q  = d - dl * 72;
        int lane = dl * 16 + (o & 15);
        int ot = o >> 4;
        u32x4 pk;
        pk.x = pack2(lo.x, lo.y); pk.y = pack2(lo.z, lo.w);
        pk.z = pack2(hi.x, hi.y); pk.w = pack2(hi.z, hi.w);
        u32x4* dst = (u32x4*)wspl + (((size_t)(g * NQ_SPL + q) * 2 + ot) * 64 + lane);
        *dst = pk;
    } else {
        int tb = t - N_SPL_CHUNK;
        const f32x4* s4 = (const f32x4*)base_w + (size_t)tb * 2;   // coalesced
        f32x4 lo = s4[0], hi = s4[1];
        int flat = tb * 8;
        int g = flat / (OG * D_DIM);            // /9216
        int r = flat - g * (OG * D_DIM);
        int o = r / D_DIM;
        int d0 = r - o * D_DIM;                 // multiple of 8
        int dl = d0 / 72;
        int q  = (d0 - dl * 72) >> 3;
        int lane = dl * 16 + (o & 15);
        int ot = o >> 4;
        u32x4 pk;
        pk.x = pack2(lo.x, lo.y); pk.y = pack2(lo.z, lo.w);
        pk.z = pack2(hi.x, hi.y); pk.w = pack2(hi.z, hi.w);
        u32x4* dst = (u32x4*)wbase + (((size_t)(g * NQ_BASE + q) * 2 + ot) * 64 + lane);
        *dst = pk;
    }
}

// ---------------------------------------------------------------------------
// Main: 256 thr = 4 waves per block; block = one (b,g) x 64 pixels.
// Wave: 16 pixels x 32 out-channels. K-loop: compile-time LDS offsets,
// fully unrollable, zero barriers.
// ---------------------------------------------------------------------------
__global__ __launch_bounds__(256, 3) void groupkan_mfma_kernel(
    const float* __restrict__ x,
    const float* __restrict__ base_b,
    const short* __restrict__ wspl,
    const short* __restrict__ wbase,
    float* __restrict__ out)
{
    __shared__ float xt[CG][4][58];   // rows y0-1..y0+2, cols -1..56 (29696 B)

    const int tid  = threadIdx.x;
    const int tile = blockIdx.x;      // 0..48
    const int bg   = blockIdx.y;
    const int b = bg >> 2, g = bg & 3;
    const int l0 = tile * 64;
    const int y0 = l0 / HWD;

    // ---- stage x tile (zero-padded halo); 64-pixel tile spans <=2 rows ----
    const float* xg = x + (size_t)(b * C_IN + g * CG) * L_PIX;
    for (int e = tid; e < CG * 4 * 58; e += 256) {
        int c  = e / 232;
        int r  = e - c * 232;
        int ry = r / 58;
        int rx = r - ry * 58;
        int y  = y0 - 1 + ry;
        int xc = rx - 1;
        float v = 0.0f;
        if (y >= 0 && y < HWD && xc >= 0 && xc < HWD)
            v = xg[(size_t)c * L_PIX + y * HWD + xc];
        xt[c][ry][rx] = v;
    }
    __syncthreads();

    const int lane = tid & 63;
    const int wid  = tid >> 6;
    const int fr   = lane & 15;       // A-row (pixel) / B,D-col (channel)
    const int dl   = lane >> 4;       // k-subblock: this lane's d-range [72dl, 72dl+72)
    const int l    = l0 + wid * 16 + fr;
    const int yy   = l / HWD;
    const int xx   = l - yy * HWD;
    const int ybase = yy - y0;        // 0..1

    // per-lane LDS base: &xt[8*dl][ybase][xx]; all chunk reads are
    // compile-time offsets from P (+232 floats per channel step)
    const float* P = (const float*)xt + (dl * 8) * 232 + ybase * 58 + xx;

    f32x4 acc0, acc1;
    {
        float b0 = base_b[g * OG + fr];
        float b1 = base_b[g * OG + 16 + fr];
        acc0 = (f32x4){b0, b0, b0, b0};
        acc1 = (f32x4){b1, b1, b1, b1};
    }

    const short8* wl  = (const short8*)wspl + (size_t)g * NQ_SPL * 2 * 64 + lane;
    const short8* wbl = (const short8*)wbase + (size_t)g * NQ_BASE * 2 * 64 + lane;

    // ---- spline: 72 chunks; chunk q=qo*9+qi -> lane's d = 72dl + q,
    //      c = 8dl + qo, patch pos kk = qi (compile-time) ----
    for (int qo = 0; qo < 8; ++qo) {
        const float* Pc = P + qo * 232;
#pragma unroll
        for (int qi = 0; qi < 9; ++qi) {
            const int kh = qi / 3, kw = qi % 3;
            float v  = Pc[kh * 58 + kw];
            float ap = v * A_SCL + A_SCL;         // (v+1)*3.5*sqrt(L)
            float e0, e1, e2, e3, e4, e5, e6, e7;
            {
                float u;
                u = ap - 0.0f * SQRT_L; e0 = __builtin_amdgcn_exp2f(-(u * u));
                u = ap - 1.0f * SQRT_L; e1 = __builtin_amdgcn_exp2f(-(u * u));
                u = ap - 2.0f * SQRT_L; e2 = __builtin_amdgcn_exp2f(-(u * u));
                u = ap - 3.0f * SQRT_L; e3 = __builtin_amdgcn_exp2f(-(u * u));
                u = ap - 4.0f * SQRT_L; e4 = __builtin_amdgcn_exp2f(-(u * u));
                u = ap - 5.0f * SQRT_L; e5 = __builtin_amdgcn_exp2f(-(u * u));
                u = ap - 6.0f * SQRT_L; e6 = __builtin_amdgcn_exp2f(-(u * u));
                u = ap - 7.0f * SQRT_L; e7 = __builtin_amdgcn_exp2f(-(u * u));
            }
            u32x4 pk;
            pk.x = pack2(e0, e1); pk.y = pack2(e2, e3);
            pk.z = pack2(e4, e5); pk.w = pack2(e6, e7);
            short8 a = __builtin_bit_cast(short8, pk);
            const int q = qo * 9 + qi;
            short8 bf0 = wl[(q * 2 + 0) * 64];
            short8 bf1 = wl[(q * 2 + 1) * 64];
            acc0 = __builtin_amdgcn_mfma_f32_16x16x32_bf16(a, bf0, acc0, 0, 0, 0);
            acc1 = __builtin_amdgcn_mfma_f32_16x16x32_bf16(a, bf1, acc1, 0, 0, 0);
        }
    }

    // ---- base: 9 chunks; lane elem j -> d = 72dl + 8q + j,
    //      c = 8dl + (8q+j)/9, kk = (8q+j)%9 (all compile-time offsets) ----
#pragma unroll
    for (int q = 0; q < 9; ++q) {
        float s0, s1, s2, s3, s4, s5, s6, s7;
#pragma unroll
        for (int j = 0; j < 8; ++j) {
            const int dd = 8 * q + j;             // 0..71
            const int co = dd / 9, kk = dd % 9;
            const int kh = kk / 3, kw = kk % 3;
            float v  = P[co * 232 + kh * 58 + kw];
            float ex = __builtin_amdgcn_exp2f(-(v * LOG2E));   // exp(-v)
            float s  = v * __builtin_amdgcn_rcpf(1.0f + ex);   // silu
            if (j == 0) s0 = s; else if (j == 1) s1 = s; else if (j == 2) s2 = s;
            else if (j == 3) s3 = s; else if (j == 4) s4 = s; else if (j == 5) s5 = s;
            else if (j == 6) s6 = s; else s7 = s;
        }
        u32x4 pk;
        pk.x = pack2(s0, s1); pk.y = pack2(s2, s3);
        pk.z = pack2(s4, s5); pk.w = pack2(s6, s7);
        short8 a = __builtin_bit_cast(short8, pk);
        short8 bf0 = wbl[(q * 2 + 0) * 64];
        short8 bf1 = wbl[(q * 2 + 1) * 64];
        acc0 = __builtin_amdgcn_mfma_f32_16x16x32_bf16(a, bf0, acc0, 0, 0, 0);
        acc1 = __builtin_amdgcn_mfma_f32_16x16x32_bf16(a, bf1, acc1, 0, 0, 0);
    }

    // ---- store: D row=(dl*4+r) -> pixel, col=fr -> channel ----
    float* outp = out + (size_t)(b * C_IN + g * OG) * L_PIX;
    int pix = l0 + wid * 16 + dl * 4;
    *(f32x4*)(outp + (size_t)fr * L_PIX + pix)        = acc0;
    *(f32x4*)(outp + (size_t)(16 + fr) * L_PIX + pix) = acc1;
}

extern "C" void kernel_launch(void* const* d_in, const int* in_sizes, int n_in,
                              void* d_out, int out_size, void* d_ws, size_t ws_size,
                              hipStream_t stream) {
    const float* x        = (const float*)d_in[0];
    const float* spline_w = (const float*)d_in[1];
    const float* base_w   = (const float*)d_in[2];
    const float* base_b   = (const float*)d_in[3];
    float* out = (float*)d_out;

    short* wspl  = (short*)d_ws;                               // 294912 shorts
    short* wbase = wspl + (size_t)G_GRP * NQ_SPL * 2 * 64 * 8; //  36864 shorts

    int conv_threads = N_SPL_CHUNK + N_BASE_CHUNK;             // 41472
    convert_w_kernel<<<(conv_threads + 255) / 256, 256, 0, stream>>>(
        spline_w, base_w, wspl, wbase);

    dim3 grid(L_PIX / 64, BATCH * G_GRP);                      // 49 x 16
    groupkan_mfma_kernel<<<grid, 256, 0, stream>>>(x, base_b, wspl, wbase, out);
}